// Round 1
// baseline (583.542 us; speedup 1.0000x reference)
//
#include <hip/hip_runtime.h>
#include <cstdint>
#include <cstddef>

// ---------------- problem constants ----------------
#define NEXP   32          // routed experts
#define TOPK   4
#define HD     1024        // hidden
#define ID     512         // intermediate
#define TT     4096        // tokens (B*S)
#define CAP    1024        // capacity per routed expert
#define SHARED_BASE (NEXP*CAP)        // 32768 : slot base of shared-expert rows
#define NSLOT  (NEXP*CAP + TT)        // 36864 total slot rows

typedef __attribute__((ext_vector_type(4))) float f32x4;
typedef __bf16 bf16x8 __attribute__((ext_vector_type(8)));

__device__ __forceinline__ unsigned short f2bf(float f) {
    union { float f; unsigned int u; } v; v.f = f;
    unsigned int u = v.u;
    u = (u + 0x7FFFu + ((u >> 16) & 1u)) >> 16;   // RNE
    return (unsigned short)u;
}
__device__ __forceinline__ float bf2f(unsigned short s) {
    union { unsigned int u; float f; } v; v.u = ((unsigned int)s) << 16;
    return v.f;
}

#define GLOAD_LDS16(g, l)                                                     \
    __builtin_amdgcn_global_load_lds(                                         \
        (__attribute__((address_space(1))) void*)(g),                         \
        (__attribute__((address_space(3))) void*)(l), 16, 0, 0)

// ---------------- fp32 -> bf16 flat convert (x) ----------------
__global__ void k_convert_x(const float* __restrict__ src,
                            unsigned short* __restrict__ dst, int n4) {
    int i = blockIdx.x * blockDim.x + threadIdx.x;
    if (i >= n4) return;
    float4 v = ((const float4*)src)[i];
    ushort4 o;
    o.x = f2bf(v.x); o.y = f2bf(v.y); o.z = f2bf(v.z); o.w = f2bf(v.w);
    ((ushort4*)dst)[i] = o;
}

// ---------------- fp32 [K][N] -> bf16 [N][K] transpose (per expert z) ------
__global__ void k_transpose_bf16(const float* __restrict__ src,
                                 unsigned short* __restrict__ dst,
                                 int K, int N) {
    __shared__ float ld[64][65];      // +1 pad: conflict-free transpose
    const size_t esz = (size_t)K * N;
    src += (size_t)blockIdx.z * esz;
    dst += (size_t)blockIdx.z * esz;
    const int n0 = blockIdx.x * 64, k0 = blockIdx.y * 64;
    const int tid = threadIdx.x;
    const int c4 = (tid & 15) * 4;
    const int rbase = tid >> 4;        // 0..15
#pragma unroll
    for (int p = 0; p < 4; p++) {
        int row = rbase + p * 16;
        float4 v = *(const float4*)(src + (size_t)(k0 + row) * N + n0 + c4);
        ld[row][c4 + 0] = v.x; ld[row][c4 + 1] = v.y;
        ld[row][c4 + 2] = v.z; ld[row][c4 + 3] = v.w;
    }
    __syncthreads();
    const int n  = tid >> 2;           // 0..63
    const int ks = (tid & 3) * 16;     // k segment
    unsigned short tmp[16];
#pragma unroll
    for (int i = 0; i < 16; i++) tmp[i] = f2bf(ld[ks + i][n]);
    uint4 a, b;
    a.x = tmp[0] | (tmp[1] << 16);  a.y = tmp[2] | (tmp[3] << 16);
    a.z = tmp[4] | (tmp[5] << 16);  a.w = tmp[6] | (tmp[7] << 16);
    b.x = tmp[8] | (tmp[9] << 16);  b.y = tmp[10] | (tmp[11] << 16);
    b.z = tmp[12] | (tmp[13] << 16); b.w = tmp[14] | (tmp[15] << 16);
    unsigned short* op = dst + (size_t)(n0 + n) * K + k0 + ks;
    *(uint4*)op = a;
    *(uint4*)(op + 8) = b;
}

// ---------------- router: fp32 logits, top-4, slot assignment --------------
__global__ __launch_bounds__(64)
void k_router(const float* __restrict__ x, const float* __restrict__ gw,
              int* __restrict__ cnt, int* __restrict__ tok,
              float* __restrict__ wgt, int* __restrict__ smap) {
    __shared__ float xs[HD];
    const int t = blockIdx.x;
    const int tid = threadIdx.x;
    const float4* x4 = (const float4*)(x + (size_t)t * HD);
    float4* xs4 = (float4*)xs;
#pragma unroll
    for (int p = 0; p < 4; p++) xs4[tid + p * 64] = x4[tid + p * 64];
    __syncthreads();
    float s = -INFINITY;
    if (tid < NEXP) {
        const float4* g4 = (const float4*)(gw + (size_t)tid * HD);
        float acc = 0.f;
        for (int i = 0; i < HD / 4; i++) {
            float4 g = g4[i]; float4 xv = xs4[i];
            acc += g.x * xv.x + g.y * xv.y + g.z * xv.z + g.w * xv.w;
        }
        s = acc;
    }
    float lv[TOPK]; int le[TOPK];
#pragma unroll
    for (int r = 0; r < TOPK; r++) {
        float m = s;
#pragma unroll
        for (int d = 1; d < 64; d <<= 1) m = fmaxf(m, __shfl_xor(m, d));
        unsigned long long ball = __ballot(s == m);
        int widx = __ffsll(ball) - 1;       // lowest lane on tie = jax top_k
        lv[r] = m; le[r] = widx;
        if (tid == widx) s = -INFINITY;
    }
    if (tid == 0) {
        float wv[TOPK], wsum = 0.f;
#pragma unroll
        for (int r = 0; r < TOPK; r++) { wv[r] = __expf(lv[r] - lv[0]); wsum += wv[r]; }
#pragma unroll
        for (int r = 0; r < TOPK; r++) {
            int e = le[r];
            int pos = atomicAdd(&cnt[e], 1);
            if (pos < CAP) {
                int slot = e * CAP + pos;
                tok[slot] = t;
                wgt[slot] = wv[r] / wsum;
                smap[t * TOPK + r] = slot;
            } else {
                smap[t * TOPK + r] = -1;     // overflow dropped (P ~ 0)
            }
        }
        tok[SHARED_BASE + t] = t;            // shared-expert identity slot
        wgt[SHARED_BASE + t] = 1.0f;
    }
}

// ---------------- grouped GEMM (m97-style 128x128, BK=32) ------------------
// A: bf16 rows [*, KD] gathered via tok (GATHER) or slot-identity.
// Bt: per-expert [1024][KD] bf16 (K-major). Experts 0..31 routed, 32 shared.
// SILU: block N covers 64 gate + 64 up columns; epilogue writes act[*,512].
// else: epilogue writes Cout[*,1024].
template <int KD, bool GATHER, bool SILU>
__global__ __launch_bounds__(256)
void k_moe_gemm(const unsigned short* __restrict__ Ab,
                const unsigned short* __restrict__ Bt,
                unsigned short* __restrict__ Cout,
                const int* __restrict__ tok,
                const int* __restrict__ cnt) {
    const int mwork = blockIdx.y;
    int e, mt;
    if (mwork < 256) { e = mwork >> 3; mt = mwork & 7; }
    else             { e = NEXP;       mt = mwork - 256; }
    const int slotbase = (e < NEXP) ? e * CAP : SHARED_BASE;
    const int cE = (e < NEXP) ? min(cnt[e], CAP) : TT;
    const int m0 = mt * 128;
    if (m0 >= cE) return;                    // uniform early-exit, pre-barrier
    const int rowsv = min(128, cE - m0);
    const int nt = blockIdx.x;

    const unsigned short* Bte = Bt + (size_t)e * (1024 * KD);

    __shared__ unsigned short As[128 * 32];
    __shared__ unsigned short Bs[128 * 32];

    const int tid  = threadIdx.x;
    const int lane = tid & 63;
    const int wv   = tid >> 6;               // wave 0..3, 32 M-rows each

    // staging: wave stages its own 32 A-rows and 32 B-rows; 16B/lane,
    // lane -> (row = lane>>2, kseg = lane&3); LDS dest = base + lane*16 (HW)
    const int rr  = lane >> 2;
    const int seg = lane & 3;
    const int r0 = wv * 32 + rr;
    const int r1 = r0 + 16;

    int ga0 = m0 + r0, ga1 = m0 + r1;
    int ra0, ra1;
    if (GATHER) {
        ra0 = (ga0 < cE) ? tok[slotbase + ga0] : 0;  // clamp: rows discarded
        ra1 = (ga1 < cE) ? tok[slotbase + ga1] : 0;
    } else {
        ra0 = slotbase + ga0;
        ra1 = slotbase + ga1;
    }
    const unsigned short* ap0 = Ab + (size_t)ra0 * KD + seg * 8;
    const unsigned short* ap1 = Ab + (size_t)ra1 * KD + seg * 8;

    int br0, br1;
    if (SILU) {   // local n<64 -> gate col nt*64+n ; n>=64 -> up col 512+...
        br0 = (r0 < 64) ? nt * 64 + r0 : 512 + nt * 64 + (r0 - 64);
        br1 = (r1 < 64) ? nt * 64 + r1 : 512 + nt * 64 + (r1 - 64);
    } else {
        br0 = nt * 128 + r0;
        br1 = nt * 128 + r1;
    }
    const unsigned short* bp0 = Bte + (size_t)br0 * KD + seg * 8;
    const unsigned short* bp1 = Bte + (size_t)br1 * KD + seg * 8;

    unsigned short* asd0 = As + (wv * 32) * 32;
    unsigned short* asd1 = As + (wv * 32 + 16) * 32;
    unsigned short* bsd0 = Bs + (wv * 32) * 32;
    unsigned short* bsd1 = Bs + (wv * 32 + 16) * 32;

    f32x4 acc[2][8];
#pragma unroll
    for (int i = 0; i < 2; i++)
#pragma unroll
        for (int j = 0; j < 8; j++) acc[i][j] = (f32x4)(0.0f);

    const int mrow = lane & 15;
    const int quad = lane >> 4;

    for (int k0 = 0; k0 < KD; k0 += 32) {
        GLOAD_LDS16(ap0 + k0, asd0);
        GLOAD_LDS16(ap1 + k0, asd1);
        GLOAD_LDS16(bp0 + k0, bsd0);
        GLOAD_LDS16(bp1 + k0, bsd1);
        __syncthreads();   // vmcnt(0) drain + barrier: LDS tiles ready
        bf16x8 af0 = *(const bf16x8*)(As + (wv * 32 + mrow) * 32 + quad * 8);
        bf16x8 af1 = *(const bf16x8*)(As + (wv * 32 + 16 + mrow) * 32 + quad * 8);
#pragma unroll
        for (int ns = 0; ns < 8; ns++) {
            bf16x8 bfr = *(const bf16x8*)(Bs + (ns * 16 + mrow) * 32 + quad * 8);
            acc[0][ns] = __builtin_amdgcn_mfma_f32_16x16x32_bf16(af0, bfr, acc[0][ns], 0, 0, 0);
            acc[1][ns] = __builtin_amdgcn_mfma_f32_16x16x32_bf16(af1, bfr, acc[1][ns], 0, 0, 0);
        }
        __syncthreads();   // all reads done before next stage overwrites
    }

    // C/D layout (verified m89/m91): col = lane&15, row = quad*4 + reg
    if (SILU) {
#pragma unroll
        for (int ms = 0; ms < 2; ms++)
#pragma unroll
            for (int ns = 0; ns < 4; ns++) {
                f32x4 g = acc[ms][ns];
                f32x4 u = acc[ms][ns + 4];
#pragma unroll
                for (int r = 0; r < 4; r++) {
                    int rloc = wv * 32 + ms * 16 + quad * 4 + r;
                    if (rloc < rowsv) {
                        float gv = g[r], uv = u[r];
                        float a = (gv / (1.f + __expf(-gv))) * uv;   // silu(g)*u
                        int c = nt * 64 + ns * 16 + mrow;
                        Cout[(size_t)(slotbase + m0 + rloc) * ID + c] = f2bf(a);
                    }
                }
            }
    } else {
#pragma unroll
        for (int ms = 0; ms < 2; ms++)
#pragma unroll
            for (int ns = 0; ns < 8; ns++) {
                f32x4 v = acc[ms][ns];
#pragma unroll
                for (int r = 0; r < 4; r++) {
                    int rloc = wv * 32 + ms * 16 + quad * 4 + r;
                    if (rloc < rowsv) {
                        int c = nt * 128 + ns * 16 + mrow;
                        Cout[(size_t)(slotbase + m0 + rloc) * HD + c] = f2bf(v[r]);
                    }
                }
            }
    }
}

// ---------------- combine: out[t] = shared + sum_k w_k * eout[slot_k] ------
__global__ __launch_bounds__(256)
void k_combine(const unsigned short* __restrict__ eout,
               const int* __restrict__ smap,
               const float* __restrict__ wgt,
               float* __restrict__ out) {
    const int t = blockIdx.x;
    const int h0 = threadIdx.x * 4;
    ushort4 q = *(const ushort4*)(eout + (size_t)(SHARED_BASE + t) * HD + h0);
    float a0 = bf2f(q.x), a1 = bf2f(q.y), a2 = bf2f(q.z), a3 = bf2f(q.w);
#pragma unroll
    for (int r = 0; r < TOPK; r++) {
        int slot = smap[t * TOPK + r];
        if (slot >= 0) {
            float w = wgt[slot];
            ushort4 e4 = *(const ushort4*)(eout + (size_t)slot * HD + h0);
            a0 += w * bf2f(e4.x); a1 += w * bf2f(e4.y);
            a2 += w * bf2f(e4.z); a3 += w * bf2f(e4.w);
        }
    }
    float4 o; o.x = a0; o.y = a1; o.z = a2; o.w = a3;
    *(float4*)(out + (size_t)t * HD + h0) = o;
}

// ---------------- launch ----------------
extern "C" void kernel_launch(void* const* d_in, const int* in_sizes, int n_in,
                              void* d_out, int out_size, void* d_ws, size_t ws_size,
                              hipStream_t stream) {
    const float* x   = (const float*)d_in[0];   // [T,H]
    const float* gw  = (const float*)d_in[1];   // [E,H]
    const float* wgu = (const float*)d_in[2];   // [E,H,2I]
    const float* wdn = (const float*)d_in[3];   // [E,I,H]
    const float* sgu = (const float*)d_in[4];   // [H,2I]
    const float* sdn = (const float*)d_in[5];   // [I,H]
    float* out = (float*)d_out;

    // workspace layout (bytes), all 256-aligned; total ~215.4 MB
    char* w = (char*)d_ws;
    size_t off = 0;
    int* cnt = (int*)(w + off);                       off += 256;
    unsigned short* xb     = (unsigned short*)(w + off); off += (size_t)TT * HD * 2;            // 8 MB
    unsigned short* wgup_t = (unsigned short*)(w + off); off += (size_t)33 * 1024 * 1024 * 2;   // 66 MB
    unsigned short* wdn_t  = (unsigned short*)(w + off); off += (size_t)33 * 1024 * 512 * 2;    // 33 MB
    unsigned short* act    = (unsigned short*)(w + off); off += (size_t)NSLOT * ID * 2;         // 36 MB
    unsigned short* eout   = (unsigned short*)(w + off); off += (size_t)NSLOT * HD * 2;         // 72 MB
    int*   tok  = (int*)(w + off);   off += (size_t)NSLOT * 4;
    float* wgt  = (float*)(w + off); off += (size_t)NSLOT * 4;
    int*   smap = (int*)(w + off);   off += (size_t)TT * TOPK * 4;

    hipMemsetAsync(cnt, 0, 256, stream);

    k_convert_x<<<(TT * HD / 4 + 255) / 256, 256, 0, stream>>>(x, xb, TT * HD / 4);

    // weights -> bf16, K-major ([N][K]); shared expert appended as expert 32
    k_transpose_bf16<<<dim3(16, 16, 32), 256, 0, stream>>>(wgu, wgup_t, 1024, 1024);
    k_transpose_bf16<<<dim3(16, 16, 1),  256, 0, stream>>>(sgu, wgup_t + (size_t)32 * 1024 * 1024, 1024, 1024);
    k_transpose_bf16<<<dim3(16, 8, 32),  256, 0, stream>>>(wdn, wdn_t, 512, 1024);
    k_transpose_bf16<<<dim3(16, 8, 1),   256, 0, stream>>>(sdn, wdn_t + (size_t)32 * 1024 * 512, 512, 1024);

    k_router<<<TT, 64, 0, stream>>>(x, gw, cnt, tok, wgt, smap);

    // GEMM1: gathered x @ gate_up^T, fused silu*mul -> act  (grid: 8 n-tiles x 288 m-works)
    k_moe_gemm<1024, true, true><<<dim3(8, 288), 256, 0, stream>>>(xb, wgup_t, act, tok, cnt);
    // GEMM2: act @ down^T -> eout
    k_moe_gemm<512, false, false><<<dim3(8, 288), 256, 0, stream>>>(act, wdn_t, eout, tok, cnt);

    k_combine<<<TT, 256, 0, stream>>>(eout, smap, wgt, out);
}

// Round 2
// 536.528 us; speedup vs baseline: 1.0876x; 1.0876x over previous
//
#include <hip/hip_runtime.h>
#include <cstdint>
#include <cstddef>

// ---------------- problem constants ----------------
#define NEXP   32          // routed experts
#define TOPK   4
#define HD     1024        // hidden
#define ID     512         // intermediate
#define TT     4096        // tokens (B*S)
#define CAP    1024        // capacity per routed expert
#define SHARED_BASE (NEXP*CAP)        // 32768 : slot base of shared-expert rows
#define NSLOT  (NEXP*CAP + TT)        // 36864 total slot rows

#define KSPLIT 16          // router split-K
#define KCH    64          // K per logits block
#define KSUB   32          // LDS sub-chunk

typedef __attribute__((ext_vector_type(4))) float f32x4;
typedef __bf16 bf16x8 __attribute__((ext_vector_type(8)));

__device__ __forceinline__ unsigned short f2bf(float f) {
    union { float f; unsigned int u; } v; v.f = f;
    unsigned int u = v.u;
    u = (u + 0x7FFFu + ((u >> 16) & 1u)) >> 16;   // RNE
    return (unsigned short)u;
}
__device__ __forceinline__ float bf2f(unsigned short s) {
    union { unsigned int u; float f; } v; v.u = ((unsigned int)s) << 16;
    return v.f;
}

#define GLOAD_LDS16(g, l)                                                     \
    __builtin_amdgcn_global_load_lds(                                         \
        (__attribute__((address_space(1))) void*)(g),                         \
        (__attribute__((address_space(3))) void*)(l), 16, 0, 0)

// ---------------- fp32 -> bf16 flat convert (x) ----------------
__global__ void k_convert_x(const float* __restrict__ src,
                            unsigned short* __restrict__ dst, int n4) {
    int i = blockIdx.x * blockDim.x + threadIdx.x;
    if (i >= n4) return;
    float4 v = ((const float4*)src)[i];
    ushort4 o;
    o.x = f2bf(v.x); o.y = f2bf(v.y); o.z = f2bf(v.z); o.w = f2bf(v.w);
    ((ushort4*)dst)[i] = o;
}

// ---------------- fp32 [K][N] -> bf16 [N][K] transpose (per expert z) ------
__global__ void k_transpose_bf16(const float* __restrict__ src,
                                 unsigned short* __restrict__ dst,
                                 int K, int N) {
    __shared__ float ld[64][65];      // +1 pad: conflict-free transpose
    const size_t esz = (size_t)K * N;
    src += (size_t)blockIdx.z * esz;
    dst += (size_t)blockIdx.z * esz;
    const int n0 = blockIdx.x * 64, k0 = blockIdx.y * 64;
    const int tid = threadIdx.x;
    const int c4 = (tid & 15) * 4;
    const int rbase = tid >> 4;        // 0..15
#pragma unroll
    for (int p = 0; p < 4; p++) {
        int row = rbase + p * 16;
        float4 v = *(const float4*)(src + (size_t)(k0 + row) * N + n0 + c4);
        ld[row][c4 + 0] = v.x; ld[row][c4 + 1] = v.y;
        ld[row][c4 + 2] = v.z; ld[row][c4 + 3] = v.w;
    }
    __syncthreads();
    const int n  = tid >> 2;           // 0..63
    const int ks = (tid & 3) * 16;     // k segment
    unsigned short tmp[16];
#pragma unroll
    for (int i = 0; i < 16; i++) tmp[i] = f2bf(ld[ks + i][n]);
    uint4 a, b;
    a.x = tmp[0] | (tmp[1] << 16);  a.y = tmp[2] | (tmp[3] << 16);
    a.z = tmp[4] | (tmp[5] << 16);  a.w = tmp[6] | (tmp[7] << 16);
    b.x = tmp[8] | (tmp[9] << 16);  b.y = tmp[10] | (tmp[11] << 16);
    b.z = tmp[12] | (tmp[13] << 16); b.w = tmp[14] | (tmp[15] << 16);
    unsigned short* op = dst + (size_t)(n0 + n) * K + k0 + ks;
    *(uint4*)op = a;
    *(uint4*)(op + 8) = b;
}

// ---------------- router part 1: fp32 logits, split-K ---------------------
// grid (16 token-chunks, KSPLIT); block 256. Thread owns 4 tokens x 8 experts.
// part[s][t][e] fp32 partial logits.
__global__ __launch_bounds__(256)
void k_logits(const float* __restrict__ x, const float* __restrict__ gw,
              float* __restrict__ part) {
    __shared__ float xsT[KSUB][260];   // stride 260: rows 16B-aligned, bank-rotated
    __shared__ float gsT[KSUB][36];
    const int tid = threadIdx.x;
    const int lane = tid & 63, wv = tid >> 6;
    const int tg = lane >> 2, eg = lane & 3;
    const int t0 = blockIdx.x * 256;
    const int kbase = blockIdx.y * KCH;
    const int tbase = wv * 64 + tg * 4;
    const int ebase = eg * 8;

    float acc[4][8];
#pragma unroll
    for (int j = 0; j < 4; j++)
#pragma unroll
        for (int i = 0; i < 8; i++) acc[j][i] = 0.f;

    for (int ks = 0; ks < KCH; ks += KSUB) {
        const int k0 = kbase + ks;
        if (ks > 0) __syncthreads();          // previous reads done
        // stage xsT: 256 tokens x KSUB k (transposed)
#pragma unroll
        for (int p = 0; p < 8; p++) {
            int vid = p * 256 + tid;          // 0..2047
            int t = vid >> 3, kq = (vid & 7) * 4;
            float4 v = *(const float4*)(x + (size_t)(t0 + t) * HD + k0 + kq);
            xsT[kq + 0][t] = v.x; xsT[kq + 1][t] = v.y;
            xsT[kq + 2][t] = v.z; xsT[kq + 3][t] = v.w;
        }
        // stage gsT: KSUB k x 32 experts (transposed)
#pragma unroll
        for (int p = 0; p < 4; p++) {
            int vid = p * 256 + tid;          // 0..1023
            int e = vid >> 5, k = vid & 31;
            gsT[k][e] = gw[(size_t)e * HD + k0 + k];
        }
        __syncthreads();
#pragma unroll 4
        for (int k = 0; k < KSUB; k++) {
            float4 xv = *(const float4*)&xsT[k][tbase];
            float4 g0 = *(const float4*)&gsT[k][ebase];
            float4 g1 = *(const float4*)&gsT[k][ebase + 4];
            float xa[4] = {xv.x, xv.y, xv.z, xv.w};
#pragma unroll
            for (int j = 0; j < 4; j++) {
                acc[j][0] += xa[j] * g0.x; acc[j][1] += xa[j] * g0.y;
                acc[j][2] += xa[j] * g0.z; acc[j][3] += xa[j] * g0.w;
                acc[j][4] += xa[j] * g1.x; acc[j][5] += xa[j] * g1.y;
                acc[j][6] += xa[j] * g1.z; acc[j][7] += xa[j] * g1.w;
            }
        }
    }
    // write partials
    const size_t base = ((size_t)blockIdx.y * TT + (t0 + tbase)) * 32 + ebase;
#pragma unroll
    for (int j = 0; j < 4; j++) {
        float4 w0, w1;
        w0.x = acc[j][0]; w0.y = acc[j][1]; w0.z = acc[j][2]; w0.w = acc[j][3];
        w1.x = acc[j][4]; w1.y = acc[j][5]; w1.z = acc[j][6]; w1.w = acc[j][7];
        *(float4*)(part + base + (size_t)j * 32) = w0;
        *(float4*)(part + base + (size_t)j * 32 + 4) = w1;
    }
}

// ---------------- router part 2: reduce partials, top-4, slots ------------
__global__ __launch_bounds__(256)
void k_topk(const float* __restrict__ part,
            int* __restrict__ cnt, int* __restrict__ tok,
            float* __restrict__ wgt, int* __restrict__ smap) {
    const int lane = threadIdx.x & 63, wv = threadIdx.x >> 6;
    const int t = blockIdx.x * 4 + wv;
    const int e = lane & 31;
    const int sbase = (lane >> 5) * 8;
    float v = 0.f;
#pragma unroll
    for (int s = 0; s < 8; s++)
        v += part[((size_t)(sbase + s) * TT + t) * 32 + e];
    v += __shfl_xor(v, 32);                 // full K sum on both halves
    float sc = (lane < 32) ? v : -INFINITY;

    float lv[TOPK]; int le[TOPK];
#pragma unroll
    for (int r = 0; r < TOPK; r++) {
        float m = sc;
#pragma unroll
        for (int d = 1; d < 64; d <<= 1) m = fmaxf(m, __shfl_xor(m, d));
        unsigned long long ball = __ballot(sc == m);
        int widx = __ffsll(ball) - 1;       // lowest lane on tie = jax top_k
        lv[r] = m; le[r] = widx;
        if (lane == widx) sc = -INFINITY;
    }
    if (lane == 0) {
        float wv4[TOPK], wsum = 0.f;
#pragma unroll
        for (int r = 0; r < TOPK; r++) { wv4[r] = __expf(lv[r] - lv[0]); wsum += wv4[r]; }
#pragma unroll
        for (int r = 0; r < TOPK; r++) {
            int ex = le[r];
            int pos = atomicAdd(&cnt[ex], 1);
            if (pos < CAP) {
                int slot = ex * CAP + pos;
                tok[slot] = t;
                wgt[slot] = wv4[r] / wsum;
                smap[t * TOPK + r] = slot;
            } else {
                smap[t * TOPK + r] = -1;     // overflow dropped (P ~ 0)
            }
        }
        tok[SHARED_BASE + t] = t;            // shared-expert identity slot
        wgt[SHARED_BASE + t] = 1.0f;
    }
}

// ---------------- grouped GEMM (m97-style 128x128, BK=32) ------------------
template <int KD, bool GATHER, bool SILU>
__global__ __launch_bounds__(256)
void k_moe_gemm(const unsigned short* __restrict__ Ab,
                const unsigned short* __restrict__ Bt,
                unsigned short* __restrict__ Cout,
                const int* __restrict__ tok,
                const int* __restrict__ cnt) {
    const int mwork = blockIdx.y;
    int e, mt;
    if (mwork < 256) { e = mwork >> 3; mt = mwork & 7; }
    else             { e = NEXP;       mt = mwork - 256; }
    const int slotbase = (e < NEXP) ? e * CAP : SHARED_BASE;
    const int cE = (e < NEXP) ? min(cnt[e], CAP) : TT;
    const int m0 = mt * 128;
    if (m0 >= cE) return;                    // uniform early-exit, pre-barrier
    const int rowsv = min(128, cE - m0);
    const int nt = blockIdx.x;

    const unsigned short* Bte = Bt + (size_t)e * (1024 * KD);

    __shared__ unsigned short As[128 * 32];
    __shared__ unsigned short Bs[128 * 32];

    const int tid  = threadIdx.x;
    const int lane = tid & 63;
    const int wv   = tid >> 6;               // wave 0..3, 32 M-rows each

    const int rr  = lane >> 2;
    const int seg = lane & 3;
    const int r0 = wv * 32 + rr;
    const int r1 = r0 + 16;

    int ga0 = m0 + r0, ga1 = m0 + r1;
    int ra0, ra1;
    if (GATHER) {
        ra0 = (ga0 < cE) ? tok[slotbase + ga0] : 0;  // clamp: rows discarded
        ra1 = (ga1 < cE) ? tok[slotbase + ga1] : 0;
    } else {
        ra0 = slotbase + ga0;
        ra1 = slotbase + ga1;
    }
    const unsigned short* ap0 = Ab + (size_t)ra0 * KD + seg * 8;
    const unsigned short* ap1 = Ab + (size_t)ra1 * KD + seg * 8;

    int br0, br1;
    if (SILU) {   // local n<64 -> gate col nt*64+n ; n>=64 -> up col 512+...
        br0 = (r0 < 64) ? nt * 64 + r0 : 512 + nt * 64 + (r0 - 64);
        br1 = (r1 < 64) ? nt * 64 + r1 : 512 + nt * 64 + (r1 - 64);
    } else {
        br0 = nt * 128 + r0;
        br1 = nt * 128 + r1;
    }
    const unsigned short* bp0 = Bte + (size_t)br0 * KD + seg * 8;
    const unsigned short* bp1 = Bte + (size_t)br1 * KD + seg * 8;

    unsigned short* asd0 = As + (wv * 32) * 32;
    unsigned short* asd1 = As + (wv * 32 + 16) * 32;
    unsigned short* bsd0 = Bs + (wv * 32) * 32;
    unsigned short* bsd1 = Bs + (wv * 32 + 16) * 32;

    f32x4 acc[2][8];
#pragma unroll
    for (int i = 0; i < 2; i++)
#pragma unroll
        for (int j = 0; j < 8; j++) acc[i][j] = (f32x4)(0.0f);

    const int mrow = lane & 15;
    const int quad = lane >> 4;

    for (int k0 = 0; k0 < KD; k0 += 32) {
        GLOAD_LDS16(ap0 + k0, asd0);
        GLOAD_LDS16(ap1 + k0, asd1);
        GLOAD_LDS16(bp0 + k0, bsd0);
        GLOAD_LDS16(bp1 + k0, bsd1);
        __syncthreads();   // vmcnt(0) drain + barrier: LDS tiles ready
        bf16x8 af0 = *(const bf16x8*)(As + (wv * 32 + mrow) * 32 + quad * 8);
        bf16x8 af1 = *(const bf16x8*)(As + (wv * 32 + 16 + mrow) * 32 + quad * 8);
#pragma unroll
        for (int ns = 0; ns < 8; ns++) {
            bf16x8 bfr = *(const bf16x8*)(Bs + (ns * 16 + mrow) * 32 + quad * 8);
            acc[0][ns] = __builtin_amdgcn_mfma_f32_16x16x32_bf16(af0, bfr, acc[0][ns], 0, 0, 0);
            acc[1][ns] = __builtin_amdgcn_mfma_f32_16x16x32_bf16(af1, bfr, acc[1][ns], 0, 0, 0);
        }
        __syncthreads();   // all reads done before next stage overwrites
    }

    // C/D layout (verified m89/m91): col = lane&15, row = quad*4 + reg
    if (SILU) {
#pragma unroll
        for (int ms = 0; ms < 2; ms++)
#pragma unroll
            for (int ns = 0; ns < 4; ns++) {
                f32x4 g = acc[ms][ns];
                f32x4 u = acc[ms][ns + 4];
#pragma unroll
                for (int r = 0; r < 4; r++) {
                    int rloc = wv * 32 + ms * 16 + quad * 4 + r;
                    if (rloc < rowsv) {
                        float gv = g[r], uv = u[r];
                        float a = (gv / (1.f + __expf(-gv))) * uv;   // silu(g)*u
                        int c = nt * 64 + ns * 16 + mrow;
                        Cout[(size_t)(slotbase + m0 + rloc) * ID + c] = f2bf(a);
                    }
                }
            }
    } else {
#pragma unroll
        for (int ms = 0; ms < 2; ms++)
#pragma unroll
            for (int ns = 0; ns < 8; ns++) {
                f32x4 v = acc[ms][ns];
#pragma unroll
                for (int r = 0; r < 4; r++) {
                    int rloc = wv * 32 + ms * 16 + quad * 4 + r;
                    if (rloc < rowsv) {
                        int c = nt * 128 + ns * 16 + mrow;
                        Cout[(size_t)(slotbase + m0 + rloc) * HD + c] = f2bf(v[r]);
                    }
                }
            }
    }
}

// ---------------- combine: out[t] = shared + sum_k w_k * eout[slot_k] ------
__global__ __launch_bounds__(256)
void k_combine(const unsigned short* __restrict__ eout,
               const int* __restrict__ smap,
               const float* __restrict__ wgt,
               float* __restrict__ out) {
    const int t = blockIdx.x;
    const int h0 = threadIdx.x * 4;
    ushort4 q = *(const ushort4*)(eout + (size_t)(SHARED_BASE + t) * HD + h0);
    float a0 = bf2f(q.x), a1 = bf2f(q.y), a2 = bf2f(q.z), a3 = bf2f(q.w);
#pragma unroll
    for (int r = 0; r < TOPK; r++) {
        int slot = smap[t * TOPK + r];
        if (slot >= 0) {
            float w = wgt[slot];
            ushort4 e4 = *(const ushort4*)(eout + (size_t)slot * HD + h0);
            a0 += w * bf2f(e4.x); a1 += w * bf2f(e4.y);
            a2 += w * bf2f(e4.z); a3 += w * bf2f(e4.w);
        }
    }
    float4 o; o.x = a0; o.y = a1; o.z = a2; o.w = a3;
    *(float4*)(out + (size_t)t * HD + h0) = o;
}

// ---------------- launch ----------------
extern "C" void kernel_launch(void* const* d_in, const int* in_sizes, int n_in,
                              void* d_out, int out_size, void* d_ws, size_t ws_size,
                              hipStream_t stream) {
    const float* x   = (const float*)d_in[0];   // [T,H]
    const float* gw  = (const float*)d_in[1];   // [E,H]
    const float* wgu = (const float*)d_in[2];   // [E,H,2I]
    const float* wdn = (const float*)d_in[3];   // [E,I,H]
    const float* sgu = (const float*)d_in[4];   // [H,2I]
    const float* sdn = (const float*)d_in[5];   // [I,H]
    float* out = (float*)d_out;

    // workspace layout (bytes), all 256-aligned; total ~215.4 MB
    char* w = (char*)d_ws;
    size_t off = 0;
    int* cnt = (int*)(w + off);                       off += 256;
    unsigned short* xb     = (unsigned short*)(w + off); off += (size_t)TT * HD * 2;            // 8 MB
    unsigned short* wgup_t = (unsigned short*)(w + off); off += (size_t)33 * 1024 * 1024 * 2;   // 66 MB
    unsigned short* wdn_t  = (unsigned short*)(w + off); off += (size_t)33 * 1024 * 512 * 2;    // 33 MB
    unsigned short* act    = (unsigned short*)(w + off); off += (size_t)NSLOT * ID * 2;         // 36 MB
    unsigned short* eout   = (unsigned short*)(w + off); off += (size_t)NSLOT * HD * 2;         // 72 MB
    int*   tok  = (int*)(w + off);   off += (size_t)NSLOT * 4;
    float* wgt  = (float*)(w + off); off += (size_t)NSLOT * 4;
    int*   smap = (int*)(w + off);   off += (size_t)TT * TOPK * 4;

    // router partials (8 MB) alias eout: part is consumed by k_topk before
    // GEMM2 produces eout — stream-ordered, no overlap.
    float* part = (float*)eout;

    hipMemsetAsync(cnt, 0, 256, stream);

    k_convert_x<<<(TT * HD / 4 + 255) / 256, 256, 0, stream>>>(x, xb, TT * HD / 4);

    // weights -> bf16, K-major ([N][K]); shared expert appended as expert 32
    k_transpose_bf16<<<dim3(16, 16, 32), 256, 0, stream>>>(wgu, wgup_t, 1024, 1024);
    k_transpose_bf16<<<dim3(16, 16, 1),  256, 0, stream>>>(sgu, wgup_t + (size_t)32 * 1024 * 1024, 1024, 1024);
    k_transpose_bf16<<<dim3(16, 8, 32),  256, 0, stream>>>(wdn, wdn_t, 512, 1024);
    k_transpose_bf16<<<dim3(16, 8, 1),   256, 0, stream>>>(sdn, wdn_t + (size_t)32 * 1024 * 512, 512, 1024);

    // router: split-K fp32 logits GEMM, then top-4 + slot assignment
    k_logits<<<dim3(16, KSPLIT), 256, 0, stream>>>(x, gw, part);
    k_topk<<<TT / 4, 256, 0, stream>>>(part, cnt, tok, wgt, smap);

    // GEMM1: gathered x @ gate_up^T, fused silu*mul -> act
    k_moe_gemm<1024, true, true><<<dim3(8, 288), 256, 0, stream>>>(xb, wgup_t, act, tok, cnt);
    // GEMM2: act @ down^T -> eout
    k_moe_gemm<512, false, false><<<dim3(8, 288), 256, 0, stream>>>(act, wdn_t, eout, tok, cnt);

    k_combine<<<TT, 256, 0, stream>>>(eout, smap, wgt, out);
}

// Round 3
// 453.192 us; speedup vs baseline: 1.2876x; 1.1839x over previous
//
#include <hip/hip_runtime.h>
#include <cstdint>
#include <cstddef>

// ---------------- problem constants ----------------
#define NEXP   32          // routed experts
#define TOPK   4
#define HD     1024        // hidden
#define ID     512         // intermediate
#define TT     4096        // tokens (B*S)
#define CAP    1024        // capacity per routed expert
#define SHARED_BASE (NEXP*CAP)        // 32768 : slot base of shared-expert rows
#define NSLOT  (NEXP*CAP + TT)        // 36864 total slot rows

#define KSPLIT 16          // router split-K
#define KCH    64          // K per logits block
#define KSUB   32          // LDS sub-chunk

typedef __attribute__((ext_vector_type(4))) float f32x4;
typedef __bf16 bf16x8 __attribute__((ext_vector_type(8)));

__device__ __forceinline__ unsigned short f2bf(float f) {
    union { float f; unsigned int u; } v; v.f = f;
    unsigned int u = v.u;
    u = (u + 0x7FFFu + ((u >> 16) & 1u)) >> 16;   // RNE
    return (unsigned short)u;
}
__device__ __forceinline__ float bf2f(unsigned short s) {
    union { unsigned int u; float f; } v; v.u = ((unsigned int)s) << 16;
    return v.f;
}

#define GLOAD_LDS16(g, l)                                                     \
    __builtin_amdgcn_global_load_lds(                                         \
        (__attribute__((address_space(1))) void*)(g),                         \
        (__attribute__((address_space(3))) void*)(l), 16, 0, 0)

// ---------------- fp32 -> bf16 flat convert (x) ----------------
__global__ void k_convert_x(const float* __restrict__ src,
                            unsigned short* __restrict__ dst, int n4) {
    int i = blockIdx.x * blockDim.x + threadIdx.x;
    if (i >= n4) return;
    float4 v = ((const float4*)src)[i];
    ushort4 o;
    o.x = f2bf(v.x); o.y = f2bf(v.y); o.z = f2bf(v.z); o.w = f2bf(v.w);
    ((ushort4*)dst)[i] = o;
}

// ---------------- fp32 [K][N] -> bf16 [N][K] transpose (per expert z) ------
__global__ void k_transpose_bf16(const float* __restrict__ src,
                                 unsigned short* __restrict__ dst,
                                 int K, int N) {
    __shared__ float ld[64][65];      // +1 pad: conflict-free transpose
    const size_t esz = (size_t)K * N;
    src += (size_t)blockIdx.z * esz;
    dst += (size_t)blockIdx.z * esz;
    const int n0 = blockIdx.x * 64, k0 = blockIdx.y * 64;
    const int tid = threadIdx.x;
    const int c4 = (tid & 15) * 4;
    const int rbase = tid >> 4;        // 0..15
#pragma unroll
    for (int p = 0; p < 4; p++) {
        int row = rbase + p * 16;
        float4 v = *(const float4*)(src + (size_t)(k0 + row) * N + n0 + c4);
        ld[row][c4 + 0] = v.x; ld[row][c4 + 1] = v.y;
        ld[row][c4 + 2] = v.z; ld[row][c4 + 3] = v.w;
    }
    __syncthreads();
    const int n  = tid >> 2;           // 0..63
    const int ks = (tid & 3) * 16;     // k segment
    unsigned short tmp[16];
#pragma unroll
    for (int i = 0; i < 16; i++) tmp[i] = f2bf(ld[ks + i][n]);
    uint4 a, b;
    a.x = tmp[0] | (tmp[1] << 16);  a.y = tmp[2] | (tmp[3] << 16);
    a.z = tmp[4] | (tmp[5] << 16);  a.w = tmp[6] | (tmp[7] << 16);
    b.x = tmp[8] | (tmp[9] << 16);  b.y = tmp[10] | (tmp[11] << 16);
    b.z = tmp[12] | (tmp[13] << 16); b.w = tmp[14] | (tmp[15] << 16);
    unsigned short* op = dst + (size_t)(n0 + n) * K + k0 + ks;
    *(uint4*)op = a;
    *(uint4*)(op + 8) = b;
}

// ---------------- router part 1: fp32 logits, split-K ---------------------
__global__ __launch_bounds__(256)
void k_logits(const float* __restrict__ x, const float* __restrict__ gw,
              float* __restrict__ part) {
    __shared__ float xsT[KSUB][260];
    __shared__ float gsT[KSUB][36];
    const int tid = threadIdx.x;
    const int lane = tid & 63, wv = tid >> 6;
    const int tg = lane >> 2, eg = lane & 3;
    const int t0 = blockIdx.x * 256;
    const int kbase = blockIdx.y * KCH;
    const int tbase = wv * 64 + tg * 4;
    const int ebase = eg * 8;

    float acc[4][8];
#pragma unroll
    for (int j = 0; j < 4; j++)
#pragma unroll
        for (int i = 0; i < 8; i++) acc[j][i] = 0.f;

    for (int ks = 0; ks < KCH; ks += KSUB) {
        const int k0 = kbase + ks;
        if (ks > 0) __syncthreads();
#pragma unroll
        for (int p = 0; p < 8; p++) {
            int vid = p * 256 + tid;
            int t = vid >> 3, kq = (vid & 7) * 4;
            float4 v = *(const float4*)(x + (size_t)(t0 + t) * HD + k0 + kq);
            xsT[kq + 0][t] = v.x; xsT[kq + 1][t] = v.y;
            xsT[kq + 2][t] = v.z; xsT[kq + 3][t] = v.w;
        }
#pragma unroll
        for (int p = 0; p < 4; p++) {
            int vid = p * 256 + tid;
            int e = vid >> 5, k = vid & 31;
            gsT[k][e] = gw[(size_t)e * HD + k0 + k];
        }
        __syncthreads();
#pragma unroll 4
        for (int k = 0; k < KSUB; k++) {
            float4 xv = *(const float4*)&xsT[k][tbase];
            float4 g0 = *(const float4*)&gsT[k][ebase];
            float4 g1 = *(const float4*)&gsT[k][ebase + 4];
            float xa[4] = {xv.x, xv.y, xv.z, xv.w};
#pragma unroll
            for (int j = 0; j < 4; j++) {
                acc[j][0] += xa[j] * g0.x; acc[j][1] += xa[j] * g0.y;
                acc[j][2] += xa[j] * g0.z; acc[j][3] += xa[j] * g0.w;
                acc[j][4] += xa[j] * g1.x; acc[j][5] += xa[j] * g1.y;
                acc[j][6] += xa[j] * g1.z; acc[j][7] += xa[j] * g1.w;
            }
        }
    }
    const size_t base = ((size_t)blockIdx.y * TT + (t0 + tbase)) * 32 + ebase;
#pragma unroll
    for (int j = 0; j < 4; j++) {
        float4 w0, w1;
        w0.x = acc[j][0]; w0.y = acc[j][1]; w0.z = acc[j][2]; w0.w = acc[j][3];
        w1.x = acc[j][4]; w1.y = acc[j][5]; w1.z = acc[j][6]; w1.w = acc[j][7];
        *(float4*)(part + base + (size_t)j * 32) = w0;
        *(float4*)(part + base + (size_t)j * 32 + 4) = w1;
    }
}

// ---------------- router part 2: reduce partials, top-4 (NO atomics) ------
__global__ __launch_bounds__(256)
void k_topk(const float* __restrict__ part,
            int* __restrict__ choice, float* __restrict__ cw,
            int* __restrict__ tok, float* __restrict__ wgt) {
    const int lane = threadIdx.x & 63, wv = threadIdx.x >> 6;
    const int t = blockIdx.x * 4 + wv;
    const int e = lane & 31;
    const int sbase = (lane >> 5) * 8;
    float v = 0.f;
#pragma unroll
    for (int s = 0; s < 8; s++)
        v += part[((size_t)(sbase + s) * TT + t) * 32 + e];
    v += __shfl_xor(v, 32);
    float sc = (lane < 32) ? v : -INFINITY;

    float lv[TOPK]; int le[TOPK];
#pragma unroll
    for (int r = 0; r < TOPK; r++) {
        float m = sc;
#pragma unroll
        for (int d = 1; d < 64; d <<= 1) m = fmaxf(m, __shfl_xor(m, d));
        unsigned long long ball = __ballot(sc == m);
        int widx = __ffsll(ball) - 1;       // lowest lane on tie = jax top_k
        lv[r] = m; le[r] = widx;
        if (lane == widx) sc = -INFINITY;
    }
    if (lane == 0) {
        float wv4[TOPK], wsum = 0.f;
#pragma unroll
        for (int r = 0; r < TOPK; r++) { wv4[r] = __expf(lv[r] - lv[0]); wsum += wv4[r]; }
#pragma unroll
        for (int r = 0; r < TOPK; r++) {
            choice[t * TOPK + r] = le[r];
            cw[t * TOPK + r] = wv4[r] / wsum;
        }
        tok[SHARED_BASE + t] = t;            // shared-expert identity slot
        wgt[SHARED_BASE + t] = 1.0f;
    }
}

// ---------------- slot assignment: deterministic ballot-scan, 1 blk/expert -
__global__ __launch_bounds__(1024)
void k_assign(const int* __restrict__ choice, const float* __restrict__ cw,
              int* __restrict__ cnt, int* __restrict__ tok,
              float* __restrict__ wgt, int* __restrict__ smap) {
    const int e = blockIdx.x;
    const int tid = threadIdx.x, lane = tid & 63, wv = tid >> 6;
    __shared__ int wtot[16];
    int running = 0;
    for (int it = 0; it < (TT * TOPK) / 1024; it++) {
        const int i = it * 1024 + tid;
        const bool match = (choice[i] == e);
        unsigned long long ball = __ballot(match);
        int wt = __popcll(ball);
        int wpre = __popcll(ball & ((1ull << lane) - 1ull));
        if (lane == 0) wtot[wv] = wt;
        __syncthreads();
        int woff = 0, tot = 0;
#pragma unroll
        for (int w = 0; w < 16; w++) { int c = wtot[w]; tot += c; if (w < wv) woff += c; }
        int pos = running + woff + wpre;
        running += tot;
        __syncthreads();
        if (match) {
            if (pos < CAP) {
                int slot = e * CAP + pos;
                tok[slot] = i >> 2;          // token id
                wgt[slot] = cw[i];
                smap[i] = slot;
            } else {
                smap[i] = -1;                // overflow dropped (P ~ 0)
            }
        }
    }
    if (tid == 0) cnt[e] = min(running, CAP);
}

// ---------------- grouped GEMM: 128x128 tile, BK=32, 2x2 waves of 64x64 ----
// LDS k-seg XOR swizzle: physical 16B slot s of row r holds k-seg s^((r>>1)&3)
// -> fragment ds_read_b128 is 2-way bank aliased (free), no conflicts.
template <int KD, bool GATHER, bool SILU>
__global__ __launch_bounds__(256)
void k_moe_gemm(const unsigned short* __restrict__ Ab,
                const unsigned short* __restrict__ Bt,
                unsigned short* __restrict__ Cout,
                const int* __restrict__ tok,
                const int* __restrict__ cnt) {
    const int mwork = blockIdx.y;
    int e, mt;
    if (mwork < 256) { e = mwork >> 3; mt = mwork & 7; }
    else             { e = NEXP;       mt = mwork - 256; }
    const int slotbase = (e < NEXP) ? e * CAP : SHARED_BASE;
    const int cE = (e < NEXP) ? min(cnt[e], CAP) : TT;
    const int m0 = mt * 128;
    if (m0 >= cE) return;                    // uniform early-exit, pre-barrier
    const int rowsv = min(128, cE - m0);
    const int nt = blockIdx.x;

    const unsigned short* Bte = Bt + (size_t)e * (1024 * KD);

    __shared__ unsigned short As[128 * 32];
    __shared__ unsigned short Bs[128 * 32];

    const int tid  = threadIdx.x;
    const int lane = tid & 63;
    const int wv   = tid >> 6;

    // staging: wave stages its 32 A-rows + 32 B-rows; swizzled k-seg choice
    const int rr  = lane >> 2;
    const int seg = (lane & 3) ^ ((lane >> 3) & 3);
    const int r0 = wv * 32 + rr;
    const int r1 = r0 + 16;

    int ga0 = m0 + r0, ga1 = m0 + r1;
    int ra0, ra1;
    if (GATHER) {
        ra0 = (ga0 < cE) ? tok[slotbase + ga0] : 0;  // clamp: rows discarded
        ra1 = (ga1 < cE) ? tok[slotbase + ga1] : 0;
    } else {
        ra0 = slotbase + ga0;
        ra1 = slotbase + ga1;
    }
    const unsigned short* ap0 = Ab + (size_t)ra0 * KD + seg * 8;
    const unsigned short* ap1 = Ab + (size_t)ra1 * KD + seg * 8;

    int br0, br1;
    if (SILU) {
        // local B row r: grp=r>>6 (wave wn), within=r&63; 0..31 -> gate col,
        // 32..63 -> matching up col (+512). Pairs g/u within each wave's frags.
        int in0 = r0 & 63, in1 = r1 & 63;
        int c0 = nt * 64 + (r0 >> 6) * 32 + (in0 & 31);
        int c1 = nt * 64 + (r1 >> 6) * 32 + (in1 & 31);
        br0 = (in0 < 32) ? c0 : 512 + c0;
        br1 = (in1 < 32) ? c1 : 512 + c1;
    } else {
        br0 = nt * 128 + r0;
        br1 = nt * 128 + r1;
    }
    const unsigned short* bp0 = Bte + (size_t)br0 * KD + seg * 8;
    const unsigned short* bp1 = Bte + (size_t)br1 * KD + seg * 8;

    unsigned short* asd0 = As + (wv * 32) * 32;
    unsigned short* asd1 = As + (wv * 32 + 16) * 32;
    unsigned short* bsd0 = Bs + (wv * 32) * 32;
    unsigned short* bsd1 = Bs + (wv * 32 + 16) * 32;

    f32x4 acc[4][4];
#pragma unroll
    for (int i = 0; i < 4; i++)
#pragma unroll
        for (int j = 0; j < 4; j++) acc[i][j] = (f32x4)(0.0f);

    const int mrow = lane & 15;
    const int quad = lane >> 4;
    const int wm = wv >> 1, wn = wv & 1;
    const int sw = (quad ^ ((mrow >> 1) & 3)) * 8;   // swizzled k-slot (elems)

    const unsigned short* aRd = As + (wm * 64 + mrow) * 32 + sw;
    const unsigned short* bRd = Bs + (wn * 64 + mrow) * 32 + sw;

    for (int k0 = 0; k0 < KD; k0 += 32) {
        GLOAD_LDS16(ap0 + k0, asd0);
        GLOAD_LDS16(ap1 + k0, asd1);
        GLOAD_LDS16(bp0 + k0, bsd0);
        GLOAD_LDS16(bp1 + k0, bsd1);
        __syncthreads();   // vmcnt(0) drain + barrier: LDS tiles ready
        bf16x8 af[4], bf[4];
#pragma unroll
        for (int i = 0; i < 4; i++) {
            af[i] = *(const bf16x8*)(aRd + i * 16 * 32);
            bf[i] = *(const bf16x8*)(bRd + i * 16 * 32);
        }
#pragma unroll
        for (int mi = 0; mi < 4; mi++)
#pragma unroll
            for (int nj = 0; nj < 4; nj++)
                acc[mi][nj] = __builtin_amdgcn_mfma_f32_16x16x32_bf16(
                    af[mi], bf[nj], acc[mi][nj], 0, 0, 0);
        __syncthreads();   // all reads done before next stage overwrites
    }

    // C/D layout (verified m89/m91): col = lane&15, row = quad*4 + reg
    if (SILU) {
#pragma unroll
        for (int mi = 0; mi < 4; mi++)
#pragma unroll
            for (int nj = 0; nj < 2; nj++) {
                f32x4 g = acc[mi][nj];
                f32x4 u = acc[mi][nj + 2];
#pragma unroll
                for (int r = 0; r < 4; r++) {
                    int rloc = wm * 64 + mi * 16 + quad * 4 + r;
                    if (rloc < rowsv) {
                        float gv = g[r], uv = u[r];
                        float a = (gv / (1.f + __expf(-gv))) * uv;   // silu(g)*u
                        int c = nt * 64 + wn * 32 + nj * 16 + mrow;
                        Cout[(size_t)(slotbase + m0 + rloc) * ID + c] = f2bf(a);
                    }
                }
            }
    } else {
#pragma unroll
        for (int mi = 0; mi < 4; mi++)
#pragma unroll
            for (int nj = 0; nj < 4; nj++) {
                f32x4 v = acc[mi][nj];
#pragma unroll
                for (int r = 0; r < 4; r++) {
                    int rloc = wm * 64 + mi * 16 + quad * 4 + r;
                    if (rloc < rowsv) {
                        int c = nt * 128 + wn * 64 + nj * 16 + mrow;
                        Cout[(size_t)(slotbase + m0 + rloc) * HD + c] = f2bf(v[r]);
                    }
                }
            }
    }
}

// ---------------- combine: out[t] = shared + sum_k w_k * eout[slot_k] ------
__global__ __launch_bounds__(256)
void k_combine(const unsigned short* __restrict__ eout,
               const int* __restrict__ smap,
               const float* __restrict__ wgt,
               float* __restrict__ out) {
    const int t = blockIdx.x;
    const int h0 = threadIdx.x * 4;
    ushort4 q = *(const ushort4*)(eout + (size_t)(SHARED_BASE + t) * HD + h0);
    float a0 = bf2f(q.x), a1 = bf2f(q.y), a2 = bf2f(q.z), a3 = bf2f(q.w);
#pragma unroll
    for (int r = 0; r < TOPK; r++) {
        int slot = smap[t * TOPK + r];
        if (slot >= 0) {
            float w = wgt[slot];
            ushort4 e4 = *(const ushort4*)(eout + (size_t)slot * HD + h0);
            a0 += w * bf2f(e4.x); a1 += w * bf2f(e4.y);
            a2 += w * bf2f(e4.z); a3 += w * bf2f(e4.w);
        }
    }
    float4 o; o.x = a0; o.y = a1; o.z = a2; o.w = a3;
    *(float4*)(out + (size_t)t * HD + h0) = o;
}

// ---------------- launch ----------------
extern "C" void kernel_launch(void* const* d_in, const int* in_sizes, int n_in,
                              void* d_out, int out_size, void* d_ws, size_t ws_size,
                              hipStream_t stream) {
    const float* x   = (const float*)d_in[0];   // [T,H]
    const float* gw  = (const float*)d_in[1];   // [E,H]
    const float* wgu = (const float*)d_in[2];   // [E,H,2I]
    const float* wdn = (const float*)d_in[3];   // [E,I,H]
    const float* sgu = (const float*)d_in[4];   // [H,2I]
    const float* sdn = (const float*)d_in[5];   // [I,H]
    float* out = (float*)d_out;

    char* w = (char*)d_ws;
    size_t off = 0;
    int* cnt = (int*)(w + off);                       off += 256;
    unsigned short* xb     = (unsigned short*)(w + off); off += (size_t)TT * HD * 2;            // 8 MB
    unsigned short* wgup_t = (unsigned short*)(w + off); off += (size_t)33 * 1024 * 1024 * 2;   // 66 MB
    unsigned short* wdn_t  = (unsigned short*)(w + off); off += (size_t)33 * 1024 * 512 * 2;    // 33 MB
    unsigned short* act    = (unsigned short*)(w + off); off += (size_t)NSLOT * ID * 2;         // 36 MB
    unsigned short* eout   = (unsigned short*)(w + off); off += (size_t)NSLOT * HD * 2;         // 72 MB
    int*   tok    = (int*)(w + off);   off += (size_t)NSLOT * 4;
    float* wgt    = (float*)(w + off); off += (size_t)NSLOT * 4;
    int*   smap   = (int*)(w + off);   off += (size_t)TT * TOPK * 4;
    int*   choice = (int*)(w + off);   off += (size_t)TT * TOPK * 4;
    float* cw     = (float*)(w + off); off += (size_t)TT * TOPK * 4;

    // router partials (8 MB) alias eout: consumed by k_topk before GEMM2
    // produces eout — stream-ordered, no overlap.
    float* part = (float*)eout;

    k_convert_x<<<(TT * HD / 4 + 255) / 256, 256, 0, stream>>>(x, xb, TT * HD / 4);

    // weights -> bf16, K-major ([N][K]); shared expert appended as expert 32
    k_transpose_bf16<<<dim3(16, 16, 32), 256, 0, stream>>>(wgu, wgup_t, 1024, 1024);
    k_transpose_bf16<<<dim3(16, 16, 1),  256, 0, stream>>>(sgu, wgup_t + (size_t)32 * 1024 * 1024, 1024, 1024);
    k_transpose_bf16<<<dim3(16, 8, 32),  256, 0, stream>>>(wdn, wdn_t, 512, 1024);
    k_transpose_bf16<<<dim3(16, 8, 1),   256, 0, stream>>>(sdn, wdn_t + (size_t)32 * 1024 * 512, 512, 1024);

    // router: split-K fp32 logits GEMM, top-4, then atomic-free slot scan
    k_logits<<<dim3(16, KSPLIT), 256, 0, stream>>>(x, gw, part);
    k_topk<<<TT / 4, 256, 0, stream>>>(part, choice, cw, tok, wgt);
    k_assign<<<NEXP, 1024, 0, stream>>>(choice, cw, cnt, tok, wgt, smap);

    // GEMM1: gathered x @ gate_up^T, fused silu*mul -> act
    k_moe_gemm<1024, true, true><<<dim3(8, 288), 256, 0, stream>>>(xb, wgup_t, act, tok, cnt);
    // GEMM2: act @ down^T -> eout
    k_moe_gemm<512, false, false><<<dim3(8, 288), 256, 0, stream>>>(act, wdn_t, eout, tok, cnt);

    k_combine<<<TT, 256, 0, stream>>>(eout, smap, wgt, out);
}

// Round 4
// 450.456 us; speedup vs baseline: 1.2954x; 1.0061x over previous
//
#include <hip/hip_runtime.h>
#include <cstdint>
#include <cstddef>

// ---------------- problem constants ----------------
#define NEXP   32          // routed experts
#define TOPK   4
#define HD     1024        // hidden
#define ID     512         // intermediate
#define TT     4096        // tokens (B*S)
#define CAP    1024        // capacity per routed expert
#define SHARED_BASE (NEXP*CAP)        // 32768 : slot base of shared-expert rows
#define NSLOT  (NEXP*CAP + TT)        // 36864 total slot rows
#define MAXTILES 320       // >= sum ceil(cE/128) + 32 (shared)

#define KSPLIT 16          // router split-K
#define KCH    64          // K per logits block
#define KSUB   32          // LDS sub-chunk

typedef __attribute__((ext_vector_type(4))) float f32x4;
typedef __bf16 bf16x8 __attribute__((ext_vector_type(8)));

__device__ __forceinline__ unsigned short f2bf(float f) {
    union { float f; unsigned int u; } v; v.f = f;
    unsigned int u = v.u;
    u = (u + 0x7FFFu + ((u >> 16) & 1u)) >> 16;   // RNE
    return (unsigned short)u;
}
__device__ __forceinline__ float bf2f(unsigned short s) {
    union { unsigned int u; float f; } v; v.u = ((unsigned int)s) << 16;
    return v.f;
}

#define GLOAD_LDS16(g, l)                                                     \
    __builtin_amdgcn_global_load_lds(                                         \
        (__attribute__((address_space(1))) void*)(g),                         \
        (__attribute__((address_space(3))) void*)(l), 16, 0, 0)

// ---------------- fp32 -> bf16 flat convert (x) ----------------
__global__ void k_convert_x(const float* __restrict__ src,
                            unsigned short* __restrict__ dst, int n4) {
    int i = blockIdx.x * blockDim.x + threadIdx.x;
    if (i >= n4) return;
    float4 v = ((const float4*)src)[i];
    ushort4 o;
    o.x = f2bf(v.x); o.y = f2bf(v.y); o.z = f2bf(v.z); o.w = f2bf(v.w);
    ((ushort4*)dst)[i] = o;
}

// ---------------- fp32 [K][N] -> bf16 [N][K] transpose (per expert z) ------
__global__ void k_transpose_bf16(const float* __restrict__ src,
                                 unsigned short* __restrict__ dst,
                                 int K, int N) {
    __shared__ float ld[64][65];      // +1 pad: conflict-free transpose
    const size_t esz = (size_t)K * N;
    src += (size_t)blockIdx.z * esz;
    dst += (size_t)blockIdx.z * esz;
    const int n0 = blockIdx.x * 64, k0 = blockIdx.y * 64;
    const int tid = threadIdx.x;
    const int c4 = (tid & 15) * 4;
    const int rbase = tid >> 4;        // 0..15
#pragma unroll
    for (int p = 0; p < 4; p++) {
        int row = rbase + p * 16;
        float4 v = *(const float4*)(src + (size_t)(k0 + row) * N + n0 + c4);
        ld[row][c4 + 0] = v.x; ld[row][c4 + 1] = v.y;
        ld[row][c4 + 2] = v.z; ld[row][c4 + 3] = v.w;
    }
    __syncthreads();
    const int n  = tid >> 2;           // 0..63
    const int ks = (tid & 3) * 16;     // k segment
    unsigned short tmp[16];
#pragma unroll
    for (int i = 0; i < 16; i++) tmp[i] = f2bf(ld[ks + i][n]);
    uint4 a, b;
    a.x = tmp[0] | (tmp[1] << 16);  a.y = tmp[2] | (tmp[3] << 16);
    a.z = tmp[4] | (tmp[5] << 16);  a.w = tmp[6] | (tmp[7] << 16);
    b.x = tmp[8] | (tmp[9] << 16);  b.y = tmp[10] | (tmp[11] << 16);
    b.z = tmp[12] | (tmp[13] << 16); b.w = tmp[14] | (tmp[15] << 16);
    unsigned short* op = dst + (size_t)(n0 + n) * K + k0 + ks;
    *(uint4*)op = a;
    *(uint4*)(op + 8) = b;
}

// ---------------- router part 1: fp32 logits, split-K ---------------------
__global__ __launch_bounds__(256)
void k_logits(const float* __restrict__ x, const float* __restrict__ gw,
              float* __restrict__ part) {
    __shared__ float xsT[KSUB][260];
    __shared__ float gsT[KSUB][36];
    const int tid = threadIdx.x;
    const int lane = tid & 63, wv = tid >> 6;
    const int tg = lane >> 2, eg = lane & 3;
    const int t0 = blockIdx.x * 256;
    const int kbase = blockIdx.y * KCH;
    const int tbase = wv * 64 + tg * 4;
    const int ebase = eg * 8;

    float acc[4][8];
#pragma unroll
    for (int j = 0; j < 4; j++)
#pragma unroll
        for (int i = 0; i < 8; i++) acc[j][i] = 0.f;

    for (int ks = 0; ks < KCH; ks += KSUB) {
        const int k0 = kbase + ks;
        if (ks > 0) __syncthreads();
#pragma unroll
        for (int p = 0; p < 8; p++) {
            int vid = p * 256 + tid;
            int t = vid >> 3, kq = (vid & 7) * 4;
            float4 v = *(const float4*)(x + (size_t)(t0 + t) * HD + k0 + kq);
            xsT[kq + 0][t] = v.x; xsT[kq + 1][t] = v.y;
            xsT[kq + 2][t] = v.z; xsT[kq + 3][t] = v.w;
        }
#pragma unroll
        for (int p = 0; p < 4; p++) {
            int vid = p * 256 + tid;
            int e = vid >> 5, k = vid & 31;
            gsT[k][e] = gw[(size_t)e * HD + k0 + k];
        }
        __syncthreads();
#pragma unroll 4
        for (int k = 0; k < KSUB; k++) {
            float4 xv = *(const float4*)&xsT[k][tbase];
            float4 g0 = *(const float4*)&gsT[k][ebase];
            float4 g1 = *(const float4*)&gsT[k][ebase + 4];
            float xa[4] = {xv.x, xv.y, xv.z, xv.w};
#pragma unroll
            for (int j = 0; j < 4; j++) {
                acc[j][0] += xa[j] * g0.x; acc[j][1] += xa[j] * g0.y;
                acc[j][2] += xa[j] * g0.z; acc[j][3] += xa[j] * g0.w;
                acc[j][4] += xa[j] * g1.x; acc[j][5] += xa[j] * g1.y;
                acc[j][6] += xa[j] * g1.z; acc[j][7] += xa[j] * g1.w;
            }
        }
    }
    const size_t base = ((size_t)blockIdx.y * TT + (t0 + tbase)) * 32 + ebase;
#pragma unroll
    for (int j = 0; j < 4; j++) {
        float4 w0, w1;
        w0.x = acc[j][0]; w0.y = acc[j][1]; w0.z = acc[j][2]; w0.w = acc[j][3];
        w1.x = acc[j][4]; w1.y = acc[j][5]; w1.z = acc[j][6]; w1.w = acc[j][7];
        *(float4*)(part + base + (size_t)j * 32) = w0;
        *(float4*)(part + base + (size_t)j * 32 + 4) = w1;
    }
}

// ---------------- router part 2: reduce partials, top-4 (NO atomics) ------
__global__ __launch_bounds__(256)
void k_topk(const float* __restrict__ part,
            int* __restrict__ choice, float* __restrict__ cw,
            int* __restrict__ tok, float* __restrict__ wgt) {
    const int lane = threadIdx.x & 63, wv = threadIdx.x >> 6;
    const int t = blockIdx.x * 4 + wv;
    const int e = lane & 31;
    const int sbase = (lane >> 5) * 8;
    float v = 0.f;
#pragma unroll
    for (int s = 0; s < 8; s++)
        v += part[((size_t)(sbase + s) * TT + t) * 32 + e];
    v += __shfl_xor(v, 32);
    float sc = (lane < 32) ? v : -INFINITY;

    float lv[TOPK]; int le[TOPK];
#pragma unroll
    for (int r = 0; r < TOPK; r++) {
        float m = sc;
#pragma unroll
        for (int d = 1; d < 64; d <<= 1) m = fmaxf(m, __shfl_xor(m, d));
        unsigned long long ball = __ballot(sc == m);
        int widx = __ffsll(ball) - 1;       // lowest lane on tie = jax top_k
        lv[r] = m; le[r] = widx;
        if (lane == widx) sc = -INFINITY;
    }
    if (lane == 0) {
        float wv4[TOPK], wsum = 0.f;
#pragma unroll
        for (int r = 0; r < TOPK; r++) { wv4[r] = __expf(lv[r] - lv[0]); wsum += wv4[r]; }
#pragma unroll
        for (int r = 0; r < TOPK; r++) {
            choice[t * TOPK + r] = le[r];
            cw[t * TOPK + r] = wv4[r] / wsum;
        }
        tok[SHARED_BASE + t] = t;            // shared-expert identity slot
        wgt[SHARED_BASE + t] = 1.0f;
    }
}

// ---------------- slot assignment: deterministic ballot-scan, 1 blk/expert -
__global__ __launch_bounds__(1024)
void k_assign(const int* __restrict__ choice, const float* __restrict__ cw,
              int* __restrict__ cnt, int* __restrict__ tok,
              float* __restrict__ wgt, int* __restrict__ smap) {
    const int e = blockIdx.x;
    const int tid = threadIdx.x, lane = tid & 63, wv = tid >> 6;
    __shared__ int wtot[16];
    int running = 0;
    for (int it = 0; it < (TT * TOPK) / 1024; it++) {
        const int i = it * 1024 + tid;
        const bool match = (choice[i] == e);
        unsigned long long ball = __ballot(match);
        int wt = __popcll(ball);
        int wpre = __popcll(ball & ((1ull << lane) - 1ull));
        if (lane == 0) wtot[wv] = wt;
        __syncthreads();
        int woff = 0, tot = 0;
#pragma unroll
        for (int w = 0; w < 16; w++) { int c = wtot[w]; tot += c; if (w < wv) woff += c; }
        int pos = running + woff + wpre;
        running += tot;
        __syncthreads();
        if (match) {
            if (pos < CAP) {
                int slot = e * CAP + pos;
                tok[slot] = i >> 2;          // token id
                wgt[slot] = cw[i];
                smap[i] = slot;
            } else {
                smap[i] = -1;                // overflow dropped (P ~ 0)
            }
        }
    }
    if (tid == 0) cnt[e] = min(running, CAP);
}

// ---------------- compact tile list: (e,mt) for all live m-tiles ----------
__global__ void k_tiles(const int* __restrict__ cnt,
                        int* __restrict__ tiles, int* __restrict__ ntiles) {
    if (threadIdx.x != 0) return;
    int j = 0;
    for (int e = 0; e <= NEXP; e++) {
        int c = (e < NEXP) ? min(cnt[e], CAP) : TT;
        int nt = (c + 127) >> 7;
        for (int mt = 0; mt < nt; mt++) tiles[j++] = (e << 8) | mt;
    }
    *ntiles = j;
}

// ---------------- grouped GEMM: 128x128 tile, BK=32, LDS double-buffer ----
// K-loop: one barrier/iter; next stage issued AFTER the barrier into the
// alternate buffer -> its vmcnt(0) drain happens a full iteration later.
// LDS k-seg XOR swizzle (slot s of row r holds seg s^((r>>1)&3)): 0 conflicts.
template <int KD, bool GATHER, bool SILU>
__global__ __launch_bounds__(256)
void k_moe_gemm(const unsigned short* __restrict__ Ab,
                const unsigned short* __restrict__ Bt,
                unsigned short* __restrict__ Cout,
                const int* __restrict__ tok,
                const int* __restrict__ cnt,
                const int* __restrict__ tiles,
                const int* __restrict__ ntiles) {
    const int j = blockIdx.y;
    if (j >= *ntiles) return;               // dead blocks grouped at tail
    const int packed = tiles[j];
    const int e = packed >> 8, mt = packed & 255;
    const int slotbase = (e < NEXP) ? e * CAP : SHARED_BASE;
    const int cE = (e < NEXP) ? min(cnt[e], CAP) : TT;
    const int m0 = mt * 128;
    const int rowsv = min(128, cE - m0);
    const int nt = blockIdx.x;

    const unsigned short* Bte = Bt + (size_t)e * (1024 * KD);

    __shared__ unsigned short As[2][128 * 32];
    __shared__ unsigned short Bs[2][128 * 32];

    const int tid  = threadIdx.x;
    const int lane = tid & 63;
    const int wv   = tid >> 6;

    // staging: wave stages its 32 A-rows + 32 B-rows; swizzled k-seg choice
    const int rr  = lane >> 2;
    const int seg = (lane & 3) ^ ((lane >> 3) & 3);
    const int r0 = wv * 32 + rr;
    const int r1 = r0 + 16;

    int ga0 = m0 + r0, ga1 = m0 + r1;
    int ra0, ra1;
    if (GATHER) {
        ra0 = (ga0 < cE) ? tok[slotbase + ga0] : 0;  // clamp: rows discarded
        ra1 = (ga1 < cE) ? tok[slotbase + ga1] : 0;
    } else {
        ra0 = slotbase + ga0;
        ra1 = slotbase + ga1;
    }
    const unsigned short* ap0 = Ab + (size_t)ra0 * KD + seg * 8;
    const unsigned short* ap1 = Ab + (size_t)ra1 * KD + seg * 8;

    int br0, br1;
    if (SILU) {
        // local B row r: 0..31 of each wave-half -> gate col, 32..63 -> up col
        int in0 = r0 & 63, in1 = r1 & 63;
        int c0 = nt * 64 + (r0 >> 6) * 32 + (in0 & 31);
        int c1 = nt * 64 + (r1 >> 6) * 32 + (in1 & 31);
        br0 = (in0 < 32) ? c0 : 512 + c0;
        br1 = (in1 < 32) ? c1 : 512 + c1;
    } else {
        br0 = nt * 128 + r0;
        br1 = nt * 128 + r1;
    }
    const unsigned short* bp0 = Bte + (size_t)br0 * KD + seg * 8;
    const unsigned short* bp1 = Bte + (size_t)br1 * KD + seg * 8;

    const int aoff0 = (wv * 32) * 32, aoff1 = (wv * 32 + 16) * 32;

    f32x4 acc[4][4];
#pragma unroll
    for (int i = 0; i < 4; i++)
#pragma unroll
        for (int j2 = 0; j2 < 4; j2++) acc[i][j2] = (f32x4)(0.0f);

    const int mrow = lane & 15;
    const int quad = lane >> 4;
    const int wm = wv >> 1, wn = wv & 1;
    const int sw = (quad ^ ((mrow >> 1) & 3)) * 8;   // swizzled k-slot (elems)

    const int aRdOff = (wm * 64 + mrow) * 32 + sw;
    const int bRdOff = (wn * 64 + mrow) * 32 + sw;

    // prologue: stage k0=0 into buffer 0
    GLOAD_LDS16(ap0, As[0] + aoff0);
    GLOAD_LDS16(ap1, As[0] + aoff1);
    GLOAD_LDS16(bp0, Bs[0] + aoff0);
    GLOAD_LDS16(bp1, Bs[0] + aoff1);

    int p = 0;
    for (int k0 = 0; k0 < KD; k0 += 32) {
        __syncthreads();   // drains stage(k0) (issued one full iter ago for k0>0)
        if (k0 + 32 < KD) {
            const int kn = k0 + 32;
            GLOAD_LDS16(ap0 + kn, As[p ^ 1] + aoff0);
            GLOAD_LDS16(ap1 + kn, As[p ^ 1] + aoff1);
            GLOAD_LDS16(bp0 + kn, Bs[p ^ 1] + aoff0);
            GLOAD_LDS16(bp1 + kn, Bs[p ^ 1] + aoff1);
        }
        bf16x8 af[4], bf[4];
#pragma unroll
        for (int i = 0; i < 4; i++) {
            af[i] = *(const bf16x8*)(As[p] + aRdOff + i * 16 * 32);
            bf[i] = *(const bf16x8*)(Bs[p] + bRdOff + i * 16 * 32);
        }
#pragma unroll
        for (int mi = 0; mi < 4; mi++)
#pragma unroll
            for (int nj = 0; nj < 4; nj++)
                acc[mi][nj] = __builtin_amdgcn_mfma_f32_16x16x32_bf16(
                    af[mi], bf[nj], acc[mi][nj], 0, 0, 0);
        p ^= 1;
        // no second barrier: next write to the buffer just read happens only
        // after the NEXT barrier, which follows all reads above.
    }

    // C/D layout (verified m89/m91): col = lane&15, row = quad*4 + reg
    if (SILU) {
#pragma unroll
        for (int mi = 0; mi < 4; mi++)
#pragma unroll
            for (int nj = 0; nj < 2; nj++) {
                f32x4 g = acc[mi][nj];
                f32x4 u = acc[mi][nj + 2];
#pragma unroll
                for (int r = 0; r < 4; r++) {
                    int rloc = wm * 64 + mi * 16 + quad * 4 + r;
                    if (rloc < rowsv) {
                        float gv = g[r], uv = u[r];
                        float a = (gv / (1.f + __expf(-gv))) * uv;   // silu(g)*u
                        int c = nt * 64 + wn * 32 + nj * 16 + mrow;
                        Cout[(size_t)(slotbase + m0 + rloc) * ID + c] = f2bf(a);
                    }
                }
            }
    } else {
#pragma unroll
        for (int mi = 0; mi < 4; mi++)
#pragma unroll
            for (int nj = 0; nj < 4; nj++) {
                f32x4 v = acc[mi][nj];
#pragma unroll
                for (int r = 0; r < 4; r++) {
                    int rloc = wm * 64 + mi * 16 + quad * 4 + r;
                    if (rloc < rowsv) {
                        int c = nt * 128 + wn * 64 + nj * 16 + mrow;
                        Cout[(size_t)(slotbase + m0 + rloc) * HD + c] = f2bf(v[r]);
                    }
                }
            }
    }
}

// ---------------- combine: out[t] = shared + sum_k w_k * eout[slot_k] ------
__global__ __launch_bounds__(256)
void k_combine(const unsigned short* __restrict__ eout,
               const int* __restrict__ smap,
               const float* __restrict__ wgt,
               float* __restrict__ out) {
    const int t = blockIdx.x;
    const int h0 = threadIdx.x * 4;
    ushort4 q = *(const ushort4*)(eout + (size_t)(SHARED_BASE + t) * HD + h0);
    float a0 = bf2f(q.x), a1 = bf2f(q.y), a2 = bf2f(q.z), a3 = bf2f(q.w);
#pragma unroll
    for (int r = 0; r < TOPK; r++) {
        int slot = smap[t * TOPK + r];
        if (slot >= 0) {
            float w = wgt[slot];
            ushort4 e4 = *(const ushort4*)(eout + (size_t)slot * HD + h0);
            a0 += w * bf2f(e4.x); a1 += w * bf2f(e4.y);
            a2 += w * bf2f(e4.z); a3 += w * bf2f(e4.w);
        }
    }
    float4 o; o.x = a0; o.y = a1; o.z = a2; o.w = a3;
    *(float4*)(out + (size_t)t * HD + h0) = o;
}

// ---------------- launch ----------------
extern "C" void kernel_launch(void* const* d_in, const int* in_sizes, int n_in,
                              void* d_out, int out_size, void* d_ws, size_t ws_size,
                              hipStream_t stream) {
    const float* x   = (const float*)d_in[0];   // [T,H]
    const float* gw  = (const float*)d_in[1];   // [E,H]
    const float* wgu = (const float*)d_in[2];   // [E,H,2I]
    const float* wdn = (const float*)d_in[3];   // [E,I,H]
    const float* sgu = (const float*)d_in[4];   // [H,2I]
    const float* sdn = (const float*)d_in[5];   // [I,H]
    float* out = (float*)d_out;

    char* w = (char*)d_ws;
    size_t off = 0;
    int* cnt = (int*)(w + off);                       off += 256;
    unsigned short* xb     = (unsigned short*)(w + off); off += (size_t)TT * HD * 2;            // 8 MB
    unsigned short* wgup_t = (unsigned short*)(w + off); off += (size_t)33 * 1024 * 1024 * 2;   // 66 MB
    unsigned short* wdn_t  = (unsigned short*)(w + off); off += (size_t)33 * 1024 * 512 * 2;    // 33 MB
    unsigned short* act    = (unsigned short*)(w + off); off += (size_t)NSLOT * ID * 2;         // 36 MB
    unsigned short* eout   = (unsigned short*)(w + off); off += (size_t)NSLOT * HD * 2;         // 72 MB
    int*   tok    = (int*)(w + off);   off += (size_t)NSLOT * 4;
    float* wgt    = (float*)(w + off); off += (size_t)NSLOT * 4;
    int*   smap   = (int*)(w + off);   off += (size_t)TT * TOPK * 4;
    int*   choice = (int*)(w + off);   off += (size_t)TT * TOPK * 4;
    float* cw     = (float*)(w + off); off += (size_t)TT * TOPK * 4;
    int*   tiles  = (int*)(w + off);   off += (size_t)MAXTILES * 4;
    int*   ntiles = (int*)(w + off);   off += 256;

    // router partials (8 MB) alias eout: consumed by k_topk before GEMM2
    // produces eout — stream-ordered, no overlap.
    float* part = (float*)eout;

    k_convert_x<<<(TT * HD / 4 + 255) / 256, 256, 0, stream>>>(x, xb, TT * HD / 4);

    // weights -> bf16, K-major ([N][K]); shared expert appended as expert 32
    k_transpose_bf16<<<dim3(16, 16, 32), 256, 0, stream>>>(wgu, wgup_t, 1024, 1024);
    k_transpose_bf16<<<dim3(16, 16, 1),  256, 0, stream>>>(sgu, wgup_t + (size_t)32 * 1024 * 1024, 1024, 1024);
    k_transpose_bf16<<<dim3(16, 8, 32),  256, 0, stream>>>(wdn, wdn_t, 512, 1024);
    k_transpose_bf16<<<dim3(16, 8, 1),   256, 0, stream>>>(sdn, wdn_t + (size_t)32 * 1024 * 512, 512, 1024);

    // router: split-K fp32 logits GEMM, top-4, atomic-free slot scan, tiles
    k_logits<<<dim3(16, KSPLIT), 256, 0, stream>>>(x, gw, part);
    k_topk<<<TT / 4, 256, 0, stream>>>(part, choice, cw, tok, wgt);
    k_assign<<<NEXP, 1024, 0, stream>>>(choice, cw, cnt, tok, wgt, smap);
    k_tiles<<<1, 64, 0, stream>>>(cnt, tiles, ntiles);

    // GEMM1: gathered x @ gate_up^T, fused silu*mul -> act
    k_moe_gemm<1024, true, true><<<dim3(8, MAXTILES), 256, 0, stream>>>(xb, wgup_t, act, tok, cnt, tiles, ntiles);
    // GEMM2: act @ down^T -> eout
    k_moe_gemm<512, false, false><<<dim3(8, MAXTILES), 256, 0, stream>>>(act, wdn_t, eout, tok, cnt, tiles, ntiles);

    k_combine<<<TT, 256, 0, stream>>>(eout, smap, wgt, out);
}